// Round 2
// baseline (594.280 us; speedup 1.0000x reference)
//
#include <hip/hip_runtime.h>

#define BATCH 8
#define PN    16384
#define NSAMP 256
#define KDIM  512
#define HID   384
#define HALF  192
#define CIN   576   // HID + HALF
#define ROWS  2048  // BATCH * NSAMP
#define BN_EPS 1e-5f

// workspace offsets (in floats)
#define OFF_GF   0
#define OFF_W1T  3072
#define OFF_W2T  224256
#define OFF_IDX  371712   /* 2048 ints */
#define OFF_H1   373760
#define OFF_H2   1160192
#define OFF_SUM1 1946624
#define OFF_SQ1  1947008
#define OFF_SUM2 1947392
#define OFF_SQ2  1947776

typedef float v2f __attribute__((ext_vector_type(2)));

// packed f32 math, bit-identical rounding to scalar fmaf/mul/sub
__device__ __forceinline__ v2f pk_sub(v2f a, v2f b) {
  v2f d;
  asm("v_pk_add_f32 %0, %1, %2 neg_lo:[0,1] neg_hi:[0,1]"
      : "=v"(d) : "v"(a), "v"(b));
  return d;
}
__device__ __forceinline__ v2f pk_mul(v2f a, v2f b) {
  v2f d;
  asm("v_pk_mul_f32 %0, %1, %2" : "=v"(d) : "v"(a), "v"(b));
  return d;
}
__device__ __forceinline__ v2f pk_fma(v2f a, v2f b, v2f c) {
  v2f d;
  asm("v_pk_fma_f32 %0, %1, %2, %3" : "=v"(d) : "v"(a), "v"(b), "v"(c));
  return d;
}

// one DPP max step: v = max(v, dpp_move(v)); invalid/masked lanes read 0,
// which is the identity for dist >= 0.
#define DPP_MAX(v, ctrl)                                                   \
  v = fmaxf(v, __int_as_float(__builtin_amdgcn_update_dpp(                 \
          0, __float_as_int(v), (ctrl), 0xf, 0xf, true)))

// ---- K1: fused FPS (blocks 0..7) + prep (blocks 8..32) --------------------
// FPS on 192-dim local_feat == FPS on 3-dim p under metric G = Wc Wc^T = LL^T.
// d(i,j) = ||L^T p_i - L^T p_j||^2 ; q = L^T p precomputed per point.
// Argmax: value-only reduce (DPP wave max -> 16 LDS slots -> tree) + rare
// claim phase. Claimers carry the winner's q into LDS so the next step's
// centroid never touches global memory (exact-equality + atomicMin index
// tie-break reproduces jnp.argmax first-index semantics exactly).
__global__ __launch_bounds__(1024) void k_main(const float* p, const float* Wc,
                                               const float* pf, const float* Wf,
                                               const float* bfe, const float* W1,
                                               const float* W2, float* ws) {
  __shared__ float s[KDIM];
  __shared__ float Msh[6];
  __shared__ __align__(16) float redv[2][16];
  __shared__ int widx[2], ncl[2];
  __shared__ int ci[2][8];
  __shared__ float cxs[2][8], cys[2][8], czs[2][8];
  int blk = blockIdx.x, t = threadIdx.x;

  if (blk >= 8) {                    // ---- prep work, hidden under FPS ----
    if (blk < 16) {                  // W1t[c][o] = W1[o][c]
      for (int sI = (blk - 8) * 1024 + t; sI < HID * CIN; sI += 8192) {
        int o = sI / CIN, c = sI % CIN;
        ws[OFF_W1T + c * HID + o] = W1[sI];
      }
    } else if (blk < 24) {           // W2t[c][o] = W2[o][c]
      for (int sI = (blk - 16) * 1024 + t; sI < HID * HID; sI += 8192) {
        int o = sI / HID, c = sI % HID;
        ws[OFF_W2T + c * HID + o] = W2[sI];
      }
    } else if (blk < 32) {           // global_feat[b] = pf[b] @ W_feat + b_feat
      int b = blk - 24;
      if (t < KDIM) s[t] = pf[b * KDIM + t];
      __syncthreads();
      if (t < HID) {
        float acc = bfe[t];
        for (int k = 0; k < KDIM; k++) acc = fmaf(s[k], Wf[k * HID + t], acc);
        ws[OFF_GF + b * HID + t] = acc;
      }
    } else {                         // zero BN sums (contiguous 1536 floats)
      for (int i = t; i < 1536; i += 1024) ws[OFF_SUM1 + i] = 0.f;
    }
    return;
  }

  // ---- FPS, one batch per block ----
  int b = blk;
  int* idx_out = (int*)(ws + OFF_IDX);

  if (t < 64) {                      // G (3x3) in fp64 + Cholesky, wave 0
    double g0 = 0, g1 = 0, g2 = 0, g3 = 0, g4 = 0, g5 = 0;
    for (int k = t; k < HALF; k += 64) {
      double w0 = (double)Wc[k];
      double w1 = (double)Wc[HALF + k];
      double w2 = (double)Wc[2 * HALF + k];
      g0 += w0 * w0; g1 += w0 * w1; g2 += w0 * w2;
      g3 += w1 * w1; g4 += w1 * w2; g5 += w2 * w2;
    }
    for (int off = 32; off; off >>= 1) {
      g0 += __shfl_down(g0, off, 64); g1 += __shfl_down(g1, off, 64);
      g2 += __shfl_down(g2, off, 64); g3 += __shfl_down(g3, off, 64);
      g4 += __shfl_down(g4, off, 64); g5 += __shfl_down(g5, off, 64);
    }
    if (t == 0) {
      double l00 = sqrt(g0);
      double l10 = g1 / l00, l20 = g2 / l00;
      double l11 = sqrt(g3 - l10 * l10);
      double l21 = (g4 - l10 * l20) / l11;
      double l22 = sqrt(g5 - l20 * l20 - l21 * l21);
      Msh[0] = (float)l00; Msh[1] = (float)l10; Msh[2] = (float)l20;
      Msh[3] = (float)l11; Msh[4] = (float)l21; Msh[5] = (float)l22;
    }
  }
  __syncthreads();
  float m00 = Msh[0], m10 = Msh[1], m20 = Msh[2];
  float m11 = Msh[3], m21 = Msh[4], m22 = Msh[5];

  const float* pb = p + b * PN * 3;
  // ownership: pair j holds global points i0=(2j)*1024+t and i1=i0+1024
  v2f qx[8], qy[8], qz[8], dist[8];
#pragma unroll
  for (int j = 0; j < 8; j++) {
    int i0 = ((2 * j) << 10) + t;
    int i1 = i0 + 1024;
    float x0 = pb[i0 * 3], y0 = pb[i0 * 3 + 1], z0 = pb[i0 * 3 + 2];
    float x1 = pb[i1 * 3], y1 = pb[i1 * 3 + 1], z1 = pb[i1 * 3 + 2];
    qx[j] = (v2f){fmaf(m00, x0, fmaf(m10, y0, m20 * z0)),
                  fmaf(m00, x1, fmaf(m10, y1, m20 * z1))};
    qy[j] = (v2f){fmaf(m11, y0, m21 * z0), fmaf(m11, y1, m21 * z1)};
    qz[j] = (v2f){m22 * z0, m22 * z1};
    dist[j] = (v2f){1e10f, 1e10f};
  }

  // seed selection buffer 1 with far=0 (thread 0 owns point 0, q in qx[0].x)
  if (t == 0) {
    widx[1] = 0; ncl[1] = 1; ci[1][0] = 0;
    cxs[1][0] = qx[0].x; cys[1][0] = qy[0].x; czs[1][0] = qz[0].x;
    widx[0] = 0x7fffffff; ncl[0] = 0;
  }
  __syncthreads();

  int par = 0;
  for (int k = 0; k < NSAMP; k++) {
    int qb = par ^ 1;                // buffer holding step-k selection
    int far = widx[qb];
    int n   = ncl[qb];
    float cx = cxs[qb][0], cy = cys[qb][0], cz = czs[qb][0];
    int c0  = ci[qb][0];
    if (c0 != far) {                 // rare: >1 claimer, slot0 lost
      bool found = false;
      int nn = n < 8 ? n : 8;
      for (int i2 = 1; i2 < nn; i2++)
        if (ci[qb][i2] == far) {
          cx = cxs[qb][i2]; cy = cys[qb][i2]; cz = czs[qb][i2]; found = true;
        }
      if (!found) {                  // ultra-rare (>8 claimers): exact fallback
        float x = pb[far * 3], y = pb[far * 3 + 1], z = pb[far * 3 + 2];
        cx = fmaf(m00, x, fmaf(m10, y, m20 * z));
        cy = fmaf(m11, y, m21 * z);
        cz = m22 * z;
      }
    }
    if (t == 0) {
      idx_out[b * NSAMP + k] = far;  // scan emits pre-update far
      widx[par] = 0x7fffffff;        // reset claim buffer for this step
      ncl[par] = 0;
    }

    v2f cxv = (v2f){cx, cx}, cyv = (v2f){cy, cy}, czv = (v2f){cz, cz};
#pragma unroll
    for (int j = 0; j < 8; j++) {    // packed distance update (v_pk_*_f32)
      v2f dx = pk_sub(qx[j], cxv);
      v2f dy = pk_sub(qy[j], cyv);
      v2f dz = pk_sub(qz[j], czv);
      v2f d  = pk_fma(dx, dx, pk_fma(dy, dy, pk_mul(dz, dz)));
      dist[j].x = fminf(dist[j].x, d.x);
      dist[j].y = fminf(dist[j].y, d.y);
    }
    // per-thread max of 16
    float a0 = fmaxf(dist[0].x, dist[0].y);
    float a1 = fmaxf(dist[1].x, dist[1].y);
    float a2 = fmaxf(dist[2].x, dist[2].y);
    float a3 = fmaxf(dist[3].x, dist[3].y);
    float a4 = fmaxf(dist[4].x, dist[4].y);
    float a5 = fmaxf(dist[5].x, dist[5].y);
    float a6 = fmaxf(dist[6].x, dist[6].y);
    float a7 = fmaxf(dist[7].x, dist[7].y);
    float b0 = fmaxf(fmaxf(a0, a1), a2);
    float b1 = fmaxf(fmaxf(a3, a4), a5);
    float tmax = fmaxf(fmaxf(b0, b1), fmaxf(a6, a7));
    // wave max via DPP (row_shr 1/2/4/8, bcast 15/31) -> lane 63
    float wv = tmax;
    DPP_MAX(wv, 0x111);
    DPP_MAX(wv, 0x112);
    DPP_MAX(wv, 0x114);
    DPP_MAX(wv, 0x118);
    DPP_MAX(wv, 0x142);
    DPP_MAX(wv, 0x143);
    if ((t & 63) == 63) redv[par][t >> 6] = wv;
    __syncthreads();                 // barrier 1: slots visible
    float4 r0 = *(const float4*)&redv[par][0];
    float4 r1 = *(const float4*)&redv[par][4];
    float4 r2 = *(const float4*)&redv[par][8];
    float4 r3 = *(const float4*)&redv[par][12];
    float g01 = fmaxf(fmaxf(r0.x, r0.y), r0.z);
    float g02 = fmaxf(fmaxf(r0.w, r1.x), r1.y);
    float g03 = fmaxf(fmaxf(r1.z, r1.w), r2.x);
    float g04 = fmaxf(fmaxf(r2.y, r2.z), r2.w);
    float g05 = fmaxf(fmaxf(r3.x, r3.y), r3.z);
    float gmax = fmaxf(fmaxf(fmaxf(g01, g02), g03),
                       fmaxf(fmaxf(g04, g05), r3.w));
    if (tmax == gmax) {              // rare claim: carry index AND q
      int mi = 0x7fffffff; float wx = 0.f, wy = 0.f, wz = 0.f;
#pragma unroll
      for (int j = 0; j < 8; j++) {
        if (dist[j].x == gmax && mi == 0x7fffffff) {
          mi = ((2 * j) << 10) + t; wx = qx[j].x; wy = qy[j].x; wz = qz[j].x;
        }
        if (dist[j].y == gmax && mi == 0x7fffffff) {
          mi = ((2 * j + 1) << 10) + t; wx = qx[j].y; wy = qy[j].y; wz = qz[j].y;
        }
      }
      int pos = atomicAdd(&ncl[par], 1);
      if (pos < 8) {
        ci[par][pos] = mi;
        cxs[par][pos] = wx; cys[par][pos] = wy; czs[par][pos] = wz;
      }
      atomicMin(&widx[par], mi);     // smallest global index wins => argmax
    }
    __syncthreads();                 // barrier 2: selection resolved
    par ^= 1;
  }
}

// ---- K2: GEMM1 (fused gather of combined) + bias + BN1 sums --------------
__global__ __launch_bounds__(384) void k_gemm1(const float* p,
                                               const float* Wc,
                                               const float* bc,
                                               const float* b1,
                                               float* ws) {
  __shared__ __align__(16) float ct[CIN * 8];
  int t = threadIdx.x;
  int row0 = blockIdx.x * 8;
  const int* fidx = (const int*)(ws + OFF_IDX);
  for (int sI = t; sI < 8 * CIN; sI += 384) {  // stage tile transposed ct[c*8+r]
    int r = sI / CIN, c = sI % CIN;
    int row = row0 + r, b = row >> 8;
    float val;
    if (c < HID) {
      val = ws[OFF_GF + b * HID + c];          // broadcast global_feat
    } else {
      int co = c - HID;
      int i = fidx[row];
      const float* pp = p + (b * PN + i) * 3;
      val = bc[co];
      val = fmaf(pp[0], Wc[co], val);
      val = fmaf(pp[1], Wc[HALF + co], val);
      val = fmaf(pp[2], Wc[2 * HALF + co], val);  // sampled local_feat
    }
    ct[c * 8 + r] = val;
  }
  __syncthreads();
  const float* w1t = ws + OFF_W1T;
  float acc[8] = {0.f, 0.f, 0.f, 0.f, 0.f, 0.f, 0.f, 0.f};
  for (int c = 0; c < CIN; c++) {
    float w = w1t[c * HID + t];
    float4 a0 = *(const float4*)(ct + c * 8);
    float4 a1 = *(const float4*)(ct + c * 8 + 4);
    acc[0] = fmaf(a0.x, w, acc[0]); acc[1] = fmaf(a0.y, w, acc[1]);
    acc[2] = fmaf(a0.z, w, acc[2]); acc[3] = fmaf(a0.w, w, acc[3]);
    acc[4] = fmaf(a1.x, w, acc[4]); acc[5] = fmaf(a1.y, w, acc[5]);
    acc[6] = fmaf(a1.z, w, acc[6]); acc[7] = fmaf(a1.w, w, acc[7]);
  }
  float bias = b1[t];
  float sv = 0.f, sq = 0.f;
#pragma unroll
  for (int r = 0; r < 8; r++) {
    float v = acc[r] + bias;
    ws[OFF_H1 + (row0 + r) * HID + t] = v;
    sv += v; sq = fmaf(v, v, sq);
  }
  atomicAdd(&ws[OFF_SUM1 + t], sv);
  atomicAdd(&ws[OFF_SQ1 + t], sq);
}

// ---- K3: GEMM2 with inline BN1 finalize + ReLU on load -------------------
__global__ __launch_bounds__(384) void k_gemm2(const float* b2,
                                               const float* g1,
                                               const float* be1,
                                               float* ws) {
  __shared__ __align__(16) float ht[HID * 8];
  __shared__ float sc1s[HID], sh1s[HID];
  int t = threadIdx.x;
  int row0 = blockIdx.x * 8;
  {                                   // BN1 finalize, redundantly per block
    float m = ws[OFF_SUM1 + t] * (1.f / ROWS);
    float v = ws[OFF_SQ1 + t] * (1.f / ROWS) - m * m;
    float inv = 1.f / sqrtf(v + BN_EPS);
    float sc = inv * g1[t];
    sc1s[t] = sc;
    sh1s[t] = be1[t] - m * sc;
  }
  __syncthreads();
  for (int sI = t; sI < 8 * HID; sI += 384) {
    int r = sI / HID, c = sI % HID;
    float x = fmaf(ws[OFF_H1 + (row0 + r) * HID + c], sc1s[c], sh1s[c]);
    ht[c * 8 + r] = fmaxf(x, 0.f);
  }
  __syncthreads();
  const float* w2t = ws + OFF_W2T;
  float acc[8] = {0.f, 0.f, 0.f, 0.f, 0.f, 0.f, 0.f, 0.f};
  for (int c = 0; c < HID; c++) {
    float w = w2t[c * HID + t];
    float4 a0 = *(const float4*)(ht + c * 8);
    float4 a1 = *(const float4*)(ht + c * 8 + 4);
    acc[0] = fmaf(a0.x, w, acc[0]); acc[1] = fmaf(a0.y, w, acc[1]);
    acc[2] = fmaf(a0.z, w, acc[2]); acc[3] = fmaf(a0.w, w, acc[3]);
    acc[4] = fmaf(a1.x, w, acc[4]); acc[5] = fmaf(a1.y, w, acc[5]);
    acc[6] = fmaf(a1.z, w, acc[6]); acc[7] = fmaf(a1.w, w, acc[7]);
  }
  float bias = b2[t];
  float sv = 0.f, sq = 0.f;
#pragma unroll
  for (int r = 0; r < 8; r++) {
    float v = acc[r] + bias;
    ws[OFF_H2 + (row0 + r) * HID + t] = v;
    sv += v; sq = fmaf(v, v, sq);
  }
  atomicAdd(&ws[OFF_SUM2 + t], sv);
  atomicAdd(&ws[OFF_SQ2 + t], sq);
}

// ---- K4: inline BN2 finalize + affine + ReLU -----------------------------
__global__ __launch_bounds__(256) void k_out(const float* ws, const float* g2,
                                             const float* be2, float* out) {
  int gid = blockIdx.x * 256 + threadIdx.x;
  int i = gid * 4;
  int c = i % HID;                    // multiple of 4
  float4 h  = *(const float4*)(ws + OFF_H2 + i);
  float4 s2 = *(const float4*)(ws + OFF_SUM2 + c);
  float4 q2 = *(const float4*)(ws + OFF_SQ2 + c);
  float4 gv = *(const float4*)(g2 + c);
  float4 bv = *(const float4*)(be2 + c);
  float4 r;
#define BN2(comp) {                                                  \
    float m  = s2.comp * (1.f / ROWS);                               \
    float v  = q2.comp * (1.f / ROWS) - m * m;                       \
    float sc = (1.f / sqrtf(v + BN_EPS)) * gv.comp;                  \
    float sh = bv.comp - m * sc;                                     \
    r.comp = fmaxf(fmaf(h.comp, sc, sh), 0.f); }
  BN2(x) BN2(y) BN2(z) BN2(w)
#undef BN2
  ((float4*)out)[gid] = r;
}

extern "C" void kernel_launch(void* const* d_in, const int* in_sizes, int n_in,
                              void* d_out, int out_size, void* d_ws, size_t ws_size,
                              hipStream_t stream) {
  const float* p   = (const float*)d_in[0];
  // d_in[1] = N (int scalar, always 256)
  const float* pf  = (const float*)d_in[2];
  const float* Wf  = (const float*)d_in[3];
  const float* bfe = (const float*)d_in[4];
  const float* Wc  = (const float*)d_in[5];
  const float* bc  = (const float*)d_in[6];
  const float* W1  = (const float*)d_in[7];
  const float* b1  = (const float*)d_in[8];
  const float* g1  = (const float*)d_in[9];
  const float* be1 = (const float*)d_in[10];
  const float* W2  = (const float*)d_in[11];
  const float* b2  = (const float*)d_in[12];
  const float* g2  = (const float*)d_in[13];
  const float* be2 = (const float*)d_in[14];
  float* ws = (float*)d_ws;

  hipLaunchKernelGGL(k_main,  dim3(33),  dim3(1024), 0, stream,
                     p, Wc, pf, Wf, bfe, W1, W2, ws);
  hipLaunchKernelGGL(k_gemm1, dim3(256), dim3(384), 0, stream, p, Wc, bc, b1, ws);
  hipLaunchKernelGGL(k_gemm2, dim3(256), dim3(384), 0, stream, b2, g1, be1, ws);
  hipLaunchKernelGGL(k_out,   dim3(768), dim3(256), 0, stream,
                     ws, g2, be2, (float*)d_out);
}

// Round 3
// 561.943 us; speedup vs baseline: 1.0575x; 1.0575x over previous
//
#include <hip/hip_runtime.h>

#define BATCH 8
#define PN    16384
#define NSAMP 256
#define KDIM  512
#define HID   384
#define HALF  192
#define CIN   576   // HID + HALF
#define ROWS  2048  // BATCH * NSAMP
#define BN_EPS 1e-5f

// workspace offsets (in floats)
#define OFF_GF   0
#define OFF_W1T  3072
#define OFF_W2T  224256
#define OFF_IDX  371712   /* 2048 ints */
#define OFF_H1   373760
#define OFF_H2   1160192
#define OFF_SUM1 1946624
#define OFF_SQ1  1947008
#define OFF_SUM2 1947392
#define OFF_SQ2  1947776

typedef float v2f __attribute__((ext_vector_type(2)));

// d = (qx-cx)^2 + (qy-cy)^2 + (qz-cz)^2, packed 2-wide, as ONE asm block
// (block-internal deps only; blocks independent across j -> scheduler ILP).
// v_pk_add with neg on src1 == IEEE sub; same op order as scalar version =>
// bit-identical distances => identical FPS selections.
__device__ __forceinline__ v2f dist2_pk(v2f qx, v2f qy, v2f qz,
                                        v2f cx, v2f cy, v2f cz) {
  v2f dx, dy, dz, d;
  asm("v_pk_add_f32 %0, %4, %7 neg_lo:[0,1] neg_hi:[0,1]\n\t"
      "v_pk_add_f32 %1, %5, %8 neg_lo:[0,1] neg_hi:[0,1]\n\t"
      "v_pk_add_f32 %2, %6, %9 neg_lo:[0,1] neg_hi:[0,1]\n\t"
      "v_pk_mul_f32 %3, %2, %2\n\t"
      "v_pk_fma_f32 %3, %1, %1, %3\n\t"
      "v_pk_fma_f32 %3, %0, %0, %3"
      : "=&v"(dx), "=&v"(dy), "=&v"(dz), "=&v"(d)
      : "v"(qx), "v"(qy), "v"(qz), "v"(cx), "v"(cy), "v"(cz));
  return d;
}

// one DPP max step: v = max(v, dpp_move(v)); invalid/masked lanes read 0,
// identity for dist >= 0. Sequence proven correct on gfx950 in prior round.
#define DPP_MAX(v, ctrl)                                                   \
  v = fmaxf(v, __int_as_float(__builtin_amdgcn_update_dpp(                 \
          0, __float_as_int(v), (ctrl), 0xf, 0xf, true)))

// ---- K1: fused FPS (blocks 0..7) + prep (blocks 8..32) --------------------
// FPS on 192-dim local_feat == FPS on 3-dim p under metric G = Wc Wc^T = LL^T.
// d(i,j) = ||L^T p_i - L^T p_j||^2 ; q = L^T p precomputed per point.
// Argmax: value-only reduce (per-thread max3 tree -> DPP wave max -> 16 LDS
// slots -> tree) + rare claim phase. Claimers carry {index, q} into an LDS
// slot via INDEPENDENT predicated selects in descending index order (last
// write = smallest index = jnp.argmax first-index semantics), so the next
// step's centroid is one broadcast ds_read_b128 instead of an LDS->global->
// transform chain. atomicMin on index keeps exactness with multi-claimers.
__global__ __launch_bounds__(1024) void k_main(const float* p, const float* Wc,
                                               const float* pf, const float* Wf,
                                               const float* bfe, const float* W1,
                                               const float* W2, float* ws) {
  __shared__ float s[KDIM];
  __shared__ float Msh[6];
  __shared__ __align__(16) float redv[2][16];
  __shared__ __align__(16) float4 cslot[2][8];
  __shared__ int widx[2], ncl[2];
  int blk = blockIdx.x, t = threadIdx.x;

  if (blk >= 8) {                    // ---- prep work, hidden under FPS ----
    if (blk < 16) {                  // W1t[c][o] = W1[o][c]
      for (int sI = (blk - 8) * 1024 + t; sI < HID * CIN; sI += 8192) {
        int o = sI / CIN, c = sI % CIN;
        ws[OFF_W1T + c * HID + o] = W1[sI];
      }
    } else if (blk < 24) {           // W2t[c][o] = W2[o][c]
      for (int sI = (blk - 16) * 1024 + t; sI < HID * HID; sI += 8192) {
        int o = sI / HID, c = sI % HID;
        ws[OFF_W2T + c * HID + o] = W2[sI];
      }
    } else if (blk < 32) {           // global_feat[b] = pf[b] @ W_feat + b_feat
      int b = blk - 24;
      if (t < KDIM) s[t] = pf[b * KDIM + t];
      __syncthreads();
      if (t < HID) {
        float acc = bfe[t];
        for (int k = 0; k < KDIM; k++) acc = fmaf(s[k], Wf[k * HID + t], acc);
        ws[OFF_GF + b * HID + t] = acc;
      }
    } else {                         // zero BN sums (contiguous 1536 floats)
      for (int i = t; i < 1536; i += 1024) ws[OFF_SUM1 + i] = 0.f;
    }
    return;
  }

  // ---- FPS, one batch per block ----
  int b = blk;
  int* idx_out = (int*)(ws + OFF_IDX);

  if (t < 64) {                      // G (3x3) in fp64 + Cholesky, wave 0
    double g0 = 0, g1 = 0, g2 = 0, g3 = 0, g4 = 0, g5 = 0;
    for (int k = t; k < HALF; k += 64) {
      double w0 = (double)Wc[k];
      double w1 = (double)Wc[HALF + k];
      double w2 = (double)Wc[2 * HALF + k];
      g0 += w0 * w0; g1 += w0 * w1; g2 += w0 * w2;
      g3 += w1 * w1; g4 += w1 * w2; g5 += w2 * w2;
    }
    for (int off = 32; off; off >>= 1) {
      g0 += __shfl_down(g0, off, 64); g1 += __shfl_down(g1, off, 64);
      g2 += __shfl_down(g2, off, 64); g3 += __shfl_down(g3, off, 64);
      g4 += __shfl_down(g4, off, 64); g5 += __shfl_down(g5, off, 64);
    }
    if (t == 0) {
      double l00 = sqrt(g0);
      double l10 = g1 / l00, l20 = g2 / l00;
      double l11 = sqrt(g3 - l10 * l10);
      double l21 = (g4 - l10 * l20) / l11;
      double l22 = sqrt(g5 - l20 * l20 - l21 * l21);
      Msh[0] = (float)l00; Msh[1] = (float)l10; Msh[2] = (float)l20;
      Msh[3] = (float)l11; Msh[4] = (float)l21; Msh[5] = (float)l22;
    }
  }
  __syncthreads();
  float m00 = Msh[0], m10 = Msh[1], m20 = Msh[2];
  float m11 = Msh[3], m21 = Msh[4], m22 = Msh[5];

  const float* pb = p + b * PN * 3;
  // ownership: pair j holds global points i0=(2j)*1024+t and i1=i0+1024
  v2f qx[8], qy[8], qz[8], dist[8];
#pragma unroll
  for (int j = 0; j < 8; j++) {
    int i0 = ((2 * j) << 10) + t;
    int i1 = i0 + 1024;
    float x0 = pb[i0 * 3], y0 = pb[i0 * 3 + 1], z0 = pb[i0 * 3 + 2];
    float x1 = pb[i1 * 3], y1 = pb[i1 * 3 + 1], z1 = pb[i1 * 3 + 2];
    qx[j] = (v2f){fmaf(m00, x0, fmaf(m10, y0, m20 * z0)),
                  fmaf(m00, x1, fmaf(m10, y1, m20 * z1))};
    qy[j] = (v2f){fmaf(m11, y0, m21 * z0), fmaf(m11, y1, m21 * z1)};
    qz[j] = (v2f){m22 * z0, m22 * z1};
    dist[j] = (v2f){1e10f, 1e10f};
  }

  // seed selection buffer 1 with far=0 (thread 0 owns point 0, q in qx[0].x)
  if (t == 0) {
    widx[1] = 0; ncl[1] = 1;
    cslot[1][0] = make_float4(__int_as_float(0), qx[0].x, qy[0].x, qz[0].x);
    widx[0] = 0x7fffffff; ncl[0] = 0;
  }
  __syncthreads();

  int par = 0;
  for (int k = 0; k < NSAMP; k++) {
    int qb = par ^ 1;                // buffer holding step-k selection
    int far = widx[qb];
    float4 s0 = cslot[qb][0];        // broadcast ds_read_b128
    float cx = s0.y, cy = s0.z, cz = s0.w;
    if (__float_as_int(s0.x) != far) {  // rare: >1 claimer, slot0 lost
      int n = ncl[qb];
      bool found = false;
      int nn = n < 8 ? n : 8;
      for (int i2 = 1; i2 < nn; i2++) {
        float4 si = cslot[qb][i2];
        if (__float_as_int(si.x) == far) {
          cx = si.y; cy = si.z; cz = si.w; found = true;
        }
      }
      if (!found) {                  // ultra-rare (>8 claimers): exact fallback
        float x = pb[far * 3], y = pb[far * 3 + 1], z = pb[far * 3 + 2];
        cx = fmaf(m00, x, fmaf(m10, y, m20 * z));
        cy = fmaf(m11, y, m21 * z);
        cz = m22 * z;
      }
    }
    if (t == 0) {
      idx_out[b * NSAMP + k] = far;  // scan emits pre-update far
      widx[par] = 0x7fffffff;        // reset claim buffer for this step
      ncl[par] = 0;
    }

    v2f cxv = (v2f){cx, cx}, cyv = (v2f){cy, cy}, czv = (v2f){cz, cz};
#pragma unroll
    for (int j = 0; j < 8; j++) {    // packed distance update (v_pk_*_f32)
      v2f d = dist2_pk(qx[j], qy[j], qz[j], cxv, cyv, czv);
      dist[j].x = fminf(dist[j].x, d.x);
      dist[j].y = fminf(dist[j].y, d.y);
    }
    // per-thread max of 16
    float a0 = fmaxf(dist[0].x, dist[0].y);
    float a1 = fmaxf(dist[1].x, dist[1].y);
    float a2 = fmaxf(dist[2].x, dist[2].y);
    float a3 = fmaxf(dist[3].x, dist[3].y);
    float a4 = fmaxf(dist[4].x, dist[4].y);
    float a5 = fmaxf(dist[5].x, dist[5].y);
    float a6 = fmaxf(dist[6].x, dist[6].y);
    float a7 = fmaxf(dist[7].x, dist[7].y);
    float b0 = fmaxf(fmaxf(a0, a1), a2);
    float b1 = fmaxf(fmaxf(a3, a4), a5);
    float tmax = fmaxf(fmaxf(b0, b1), fmaxf(a6, a7));
    // wave max via DPP (row_shr 1/2/4/8, row_bcast 15/31) -> lane 63
    float wv = tmax;
    DPP_MAX(wv, 0x111);
    DPP_MAX(wv, 0x112);
    DPP_MAX(wv, 0x114);
    DPP_MAX(wv, 0x118);
    DPP_MAX(wv, 0x142);
    DPP_MAX(wv, 0x143);
    if ((t & 63) == 63) redv[par][t >> 6] = wv;
    __syncthreads();                 // barrier 1: slots visible
    float4 r0 = *(const float4*)&redv[par][0];
    float4 r1 = *(const float4*)&redv[par][4];
    float4 r2 = *(const float4*)&redv[par][8];
    float4 r3 = *(const float4*)&redv[par][12];
    float g01 = fmaxf(fmaxf(r0.x, r0.y), r0.z);
    float g02 = fmaxf(fmaxf(r0.w, r1.x), r1.y);
    float g03 = fmaxf(fmaxf(r1.z, r1.w), r2.x);
    float g04 = fmaxf(fmaxf(r2.y, r2.z), r2.w);
    float g05 = fmaxf(fmaxf(r3.x, r3.y), r3.z);
    float gmax = fmaxf(fmaxf(fmaxf(g01, g02), g03),
                       fmaxf(fmaxf(g04, g05), r3.w));
    if (tmax == gmax) {              // rare claim: carry index AND q
      // independent predicated selects, DESCENDING index order:
      // last executed write = smallest matching index (first-index tiebreak)
      int mi = 0x7fffffff; float wx = 0.f, wy = 0.f, wz = 0.f;
#pragma unroll
      for (int j = 7; j >= 0; j--) {
        int i0 = ((2 * j) << 10) + t;
        bool hy = (dist[j].y == gmax);
        mi = hy ? i0 + 1024 : mi;
        wx = hy ? qx[j].y : wx; wy = hy ? qy[j].y : wy; wz = hy ? qz[j].y : wz;
        bool hx = (dist[j].x == gmax);
        mi = hx ? i0 : mi;
        wx = hx ? qx[j].x : wx; wy = hx ? qy[j].x : wy; wz = hx ? qz[j].x : wz;
      }
      int pos = atomicAdd(&ncl[par], 1);
      if (pos < 8)
        cslot[par][pos] = make_float4(__int_as_float(mi), wx, wy, wz);
      atomicMin(&widx[par], mi);     // smallest global index wins => argmax
    }
    __syncthreads();                 // barrier 2: selection resolved
    par ^= 1;
  }
}

// ---- K2: GEMM1 (fused gather of combined) + bias + BN1 sums --------------
__global__ __launch_bounds__(384) void k_gemm1(const float* p,
                                               const float* Wc,
                                               const float* bc,
                                               const float* b1,
                                               float* ws) {
  __shared__ __align__(16) float ct[CIN * 8];
  int t = threadIdx.x;
  int row0 = blockIdx.x * 8;
  const int* fidx = (const int*)(ws + OFF_IDX);
  for (int sI = t; sI < 8 * CIN; sI += 384) {  // stage tile transposed ct[c*8+r]
    int r = sI / CIN, c = sI % CIN;
    int row = row0 + r, b = row >> 8;
    float val;
    if (c < HID) {
      val = ws[OFF_GF + b * HID + c];          // broadcast global_feat
    } else {
      int co = c - HID;
      int i = fidx[row];
      const float* pp = p + (b * PN + i) * 3;
      val = bc[co];
      val = fmaf(pp[0], Wc[co], val);
      val = fmaf(pp[1], Wc[HALF + co], val);
      val = fmaf(pp[2], Wc[2 * HALF + co], val);  // sampled local_feat
    }
    ct[c * 8 + r] = val;
  }
  __syncthreads();
  const float* w1t = ws + OFF_W1T;
  float acc[8] = {0.f, 0.f, 0.f, 0.f, 0.f, 0.f, 0.f, 0.f};
  for (int c = 0; c < CIN; c++) {
    float w = w1t[c * HID + t];
    float4 a0 = *(const float4*)(ct + c * 8);
    float4 a1 = *(const float4*)(ct + c * 8 + 4);
    acc[0] = fmaf(a0.x, w, acc[0]); acc[1] = fmaf(a0.y, w, acc[1]);
    acc[2] = fmaf(a0.z, w, acc[2]); acc[3] = fmaf(a0.w, w, acc[3]);
    acc[4] = fmaf(a1.x, w, acc[4]); acc[5] = fmaf(a1.y, w, acc[5]);
    acc[6] = fmaf(a1.z, w, acc[6]); acc[7] = fmaf(a1.w, w, acc[7]);
  }
  float bias = b1[t];
  float sv = 0.f, sq = 0.f;
#pragma unroll
  for (int r = 0; r < 8; r++) {
    float v = acc[r] + bias;
    ws[OFF_H1 + (row0 + r) * HID + t] = v;
    sv += v; sq = fmaf(v, v, sq);
  }
  atomicAdd(&ws[OFF_SUM1 + t], sv);
  atomicAdd(&ws[OFF_SQ1 + t], sq);
}

// ---- K3: GEMM2 with inline BN1 finalize + ReLU on load -------------------
__global__ __launch_bounds__(384) void k_gemm2(const float* b2,
                                               const float* g1,
                                               const float* be1,
                                               float* ws) {
  __shared__ __align__(16) float ht[HID * 8];
  __shared__ float sc1s[HID], sh1s[HID];
  int t = threadIdx.x;
  int row0 = blockIdx.x * 8;
  {                                   // BN1 finalize, redundantly per block
    float m = ws[OFF_SUM1 + t] * (1.f / ROWS);
    float v = ws[OFF_SQ1 + t] * (1.f / ROWS) - m * m;
    float inv = 1.f / sqrtf(v + BN_EPS);
    float sc = inv * g1[t];
    sc1s[t] = sc;
    sh1s[t] = be1[t] - m * sc;
  }
  __syncthreads();
  for (int sI = t; sI < 8 * HID; sI += 384) {
    int r = sI / HID, c = sI % HID;
    float x = fmaf(ws[OFF_H1 + (row0 + r) * HID + c], sc1s[c], sh1s[c]);
    ht[c * 8 + r] = fmaxf(x, 0.f);
  }
  __syncthreads();
  const float* w2t = ws + OFF_W2T;
  float acc[8] = {0.f, 0.f, 0.f, 0.f, 0.f, 0.f, 0.f, 0.f};
  for (int c = 0; c < HID; c++) {
    float w = w2t[c * HID + t];
    float4 a0 = *(const float4*)(ht + c * 8);
    float4 a1 = *(const float4*)(ht + c * 8 + 4);
    acc[0] = fmaf(a0.x, w, acc[0]); acc[1] = fmaf(a0.y, w, acc[1]);
    acc[2] = fmaf(a0.z, w, acc[2]); acc[3] = fmaf(a0.w, w, acc[3]);
    acc[4] = fmaf(a1.x, w, acc[4]); acc[5] = fmaf(a1.y, w, acc[5]);
    acc[6] = fmaf(a1.z, w, acc[6]); acc[7] = fmaf(a1.w, w, acc[7]);
  }
  float bias = b2[t];
  float sv = 0.f, sq = 0.f;
#pragma unroll
  for (int r = 0; r < 8; r++) {
    float v = acc[r] + bias;
    ws[OFF_H2 + (row0 + r) * HID + t] = v;
    sv += v; sq = fmaf(v, v, sq);
  }
  atomicAdd(&ws[OFF_SUM2 + t], sv);
  atomicAdd(&ws[OFF_SQ2 + t], sq);
}

// ---- K4: inline BN2 finalize + affine + ReLU -----------------------------
__global__ __launch_bounds__(256) void k_out(const float* ws, const float* g2,
                                             const float* be2, float* out) {
  int gid = blockIdx.x * 256 + threadIdx.x;
  int i = gid * 4;
  int c = i % HID;                    // multiple of 4
  float4 h  = *(const float4*)(ws + OFF_H2 + i);
  float4 s2 = *(const float4*)(ws + OFF_SUM2 + c);
  float4 q2 = *(const float4*)(ws + OFF_SQ2 + c);
  float4 gv = *(const float4*)(g2 + c);
  float4 bv = *(const float4*)(be2 + c);
  float4 r;
#define BN2(comp) {                                                  \
    float m  = s2.comp * (1.f / ROWS);                               \
    float v  = q2.comp * (1.f / ROWS) - m * m;                       \
    float sc = (1.f / sqrtf(v + BN_EPS)) * gv.comp;                  \
    float sh = bv.comp - m * sc;                                     \
    r.comp = fmaxf(fmaf(h.comp, sc, sh), 0.f); }
  BN2(x) BN2(y) BN2(z) BN2(w)
#undef BN2
  ((float4*)out)[gid] = r;
}

extern "C" void kernel_launch(void* const* d_in, const int* in_sizes, int n_in,
                              void* d_out, int out_size, void* d_ws, size_t ws_size,
                              hipStream_t stream) {
  const float* p   = (const float*)d_in[0];
  // d_in[1] = N (int scalar, always 256)
  const float* pf  = (const float*)d_in[2];
  const float* Wf  = (const float*)d_in[3];
  const float* bfe = (const float*)d_in[4];
  const float* Wc  = (const float*)d_in[5];
  const float* bc  = (const float*)d_in[6];
  const float* W1  = (const float*)d_in[7];
  const float* b1  = (const float*)d_in[8];
  const float* g1  = (const float*)d_in[9];
  const float* be1 = (const float*)d_in[10];
  const float* W2  = (const float*)d_in[11];
  const float* b2  = (const float*)d_in[12];
  const float* g2  = (const float*)d_in[13];
  const float* be2 = (const float*)d_in[14];
  float* ws = (float*)d_ws;

  hipLaunchKernelGGL(k_main,  dim3(33),  dim3(1024), 0, stream,
                     p, Wc, pf, Wf, bfe, W1, W2, ws);
  hipLaunchKernelGGL(k_gemm1, dim3(256), dim3(384), 0, stream, p, Wc, bc, b1, ws);
  hipLaunchKernelGGL(k_gemm2, dim3(256), dim3(384), 0, stream, b2, g1, be1, ws);
  hipLaunchKernelGGL(k_out,   dim3(768), dim3(256), 0, stream,
                     ws, g2, be2, (float*)d_out);
}

// Round 4
// 512.813 us; speedup vs baseline: 1.1589x; 1.0958x over previous
//
#include <hip/hip_runtime.h>

#define BATCH 8
#define PN    16384
#define NSAMP 256
#define KDIM  512
#define HID   384
#define HALF  192
#define CIN   576   // HID + HALF
#define ROWS  2048  // BATCH * NSAMP
#define BN_EPS 1e-5f

// workspace offsets (in floats)
#define OFF_GF   0
#define OFF_W1T  3072      /* local-part transpose: [192][384] = 73728 */
#define OFF_GFW  76800     /* per-batch gf@W1_glob + b1: [8][384], inside old W1T region */
#define OFF_W2T  224256
#define OFF_IDX  371712    /* 2048 ints */
#define OFF_H1   373760
#define OFF_H2   1160192
#define OFF_SUM1 1946624
#define OFF_SQ1  1947008
#define OFF_SUM2 1947392
#define OFF_SQ2  1947776

typedef float v2f __attribute__((ext_vector_type(2)));

// ---- K1: fused FPS (blocks 0..7) + prep (blocks 8..32) --------------------
// FPS on 192-dim local_feat == FPS on 3-dim p under metric G = Wc Wc^T = LL^T.
// q = L^T p per point; d(i,c) = n_i - 2<q_i,q_c> + n_c with n=|q|^2 precomputed
// (4 packed ops + 2 min per 2 points vs 6+2 for the sub-form; tolerance-safe,
// the metric trick already makes distances non-bit-identical to the 192-dim ref).
// Argmax: value-only reduce (R1's proven shuffle butterfly + 16-slot tree) +
// rare claim phase. Claimers deposit {index,q} in LDS (descending predicated
// selects => smallest index = jnp.argmax first-index tiebreak; atomicMin on
// index keeps exactness) so next step's centroid is one broadcast ds_read_b128.
__global__ __launch_bounds__(1024) void k_main(const float* p, const float* Wc,
                                               const float* pf, const float* Wf,
                                               const float* bfe, const float* W1,
                                               const float* b1v, const float* W2,
                                               float* ws) {
  __shared__ float s[KDIM];
  __shared__ float Msh[6];
  __shared__ __align__(16) float redv[2][16];
  __shared__ __align__(16) float4 cslot[2][8];
  __shared__ int widx[2], ncl[2];
  int blk = blockIdx.x, t = threadIdx.x;

  if (blk >= 8) {                    // ---- prep work, hidden under FPS ----
    if (blk < 16) {                  // W1t_loc[c][o] = W1[o][HID + c], c<192
      for (int sI = (blk - 8) * 1024 + t; sI < HID * HALF; sI += 8192) {
        int o = sI / HALF, c = sI % HALF;
        ws[OFF_W1T + c * HID + o] = W1[o * CIN + HID + c];
      }
    } else if (blk < 24) {           // W2t[c][o] = W2[o][c]
      for (int sI = (blk - 16) * 1024 + t; sI < HID * HID; sI += 8192) {
        int o = sI / HID, c = sI % HID;
        ws[OFF_W2T + c * HID + o] = W2[sI];
      }
    } else if (blk < 32) {           // gf[b] = pf[b]@W_feat + b_feat ; then
      int b = blk - 24;              // gfW[b] = b1 + gf[b]@W1_glob (per-batch)
      if (t < KDIM) s[t] = pf[b * KDIM + t];
      __syncthreads();
      float acc = 0.f;
      if (t < HID) {
        acc = bfe[t];
        for (int k = 0; k < KDIM; k++) acc = fmaf(s[k], Wf[k * HID + t], acc);
        ws[OFF_GF + b * HID + t] = acc;
      }
      __syncthreads();               // all reads of s done
      if (t < HID) s[t] = acc;       // reuse s[0..383] for gf
      __syncthreads();
      if (t < HID) {
        float g = b1v[t];
        const float* w1row = W1 + t * CIN;   // row o=t, glob channels 0..383
        for (int c = 0; c < HID; c++) g = fmaf(s[c], w1row[c], g);
        ws[OFF_GFW + b * HID + t] = g;
      }
    } else {                         // zero BN sums (contiguous 1536 floats)
      for (int i = t; i < 1536; i += 1024) ws[OFF_SUM1 + i] = 0.f;
    }
    return;
  }

  // ---- FPS, one batch per block ----
  int b = blk;
  int* idx_out = (int*)(ws + OFF_IDX);

  if (t < 64) {                      // G (3x3) in fp64 + Cholesky, wave 0
    double g0 = 0, g1 = 0, g2 = 0, g3 = 0, g4 = 0, g5 = 0;
    for (int k = t; k < HALF; k += 64) {
      double w0 = (double)Wc[k];
      double w1 = (double)Wc[HALF + k];
      double w2 = (double)Wc[2 * HALF + k];
      g0 += w0 * w0; g1 += w0 * w1; g2 += w0 * w2;
      g3 += w1 * w1; g4 += w1 * w2; g5 += w2 * w2;
    }
    for (int off = 32; off; off >>= 1) {
      g0 += __shfl_down(g0, off, 64); g1 += __shfl_down(g1, off, 64);
      g2 += __shfl_down(g2, off, 64); g3 += __shfl_down(g3, off, 64);
      g4 += __shfl_down(g4, off, 64); g5 += __shfl_down(g5, off, 64);
    }
    if (t == 0) {
      double l00 = sqrt(g0);
      double l10 = g1 / l00, l20 = g2 / l00;
      double l11 = sqrt(g3 - l10 * l10);
      double l21 = (g4 - l10 * l20) / l11;
      double l22 = sqrt(g5 - l20 * l20 - l21 * l21);
      Msh[0] = (float)l00; Msh[1] = (float)l10; Msh[2] = (float)l20;
      Msh[3] = (float)l11; Msh[4] = (float)l21; Msh[5] = (float)l22;
    }
  }
  __syncthreads();
  float m00 = Msh[0], m10 = Msh[1], m20 = Msh[2];
  float m11 = Msh[3], m21 = Msh[4], m22 = Msh[5];

  const float* pb = p + b * PN * 3;
  // ownership: pair j holds global points i0=(2j)*1024+t and i1=i0+1024
  v2f qx[8], qy[8], qz[8], nq[8], dist[8];
#pragma unroll
  for (int j = 0; j < 8; j++) {
    int i0 = ((2 * j) << 10) + t;
    int i1 = i0 + 1024;
    float x0 = pb[i0 * 3], y0 = pb[i0 * 3 + 1], z0 = pb[i0 * 3 + 2];
    float x1 = pb[i1 * 3], y1 = pb[i1 * 3 + 1], z1 = pb[i1 * 3 + 2];
    qx[j] = (v2f){fmaf(m00, x0, fmaf(m10, y0, m20 * z0)),
                  fmaf(m00, x1, fmaf(m10, y1, m20 * z1))};
    qy[j] = (v2f){fmaf(m11, y0, m21 * z0), fmaf(m11, y1, m21 * z1)};
    qz[j] = (v2f){m22 * z0, m22 * z1};
    nq[j] = __builtin_elementwise_fma(
        qx[j], qx[j],
        __builtin_elementwise_fma(qy[j], qy[j], qz[j] * qz[j]));
    dist[j] = (v2f){1e10f, 1e10f};
  }

  // seed selection buffer 1 with far=0 (thread 0 owns point 0, q in qx[0].x)
  if (t == 0) {
    widx[1] = 0; ncl[1] = 1;
    cslot[1][0] = make_float4(__int_as_float(0), qx[0].x, qy[0].x, qz[0].x);
    widx[0] = 0x7fffffff; ncl[0] = 0;
  }
  __syncthreads();

  int par = 0;
  for (int k = 0; k < NSAMP; k++) {
    int qb = par ^ 1;                // buffer holding step-k selection
    int far = widx[qb];
    float4 s0 = cslot[qb][0];        // broadcast ds_read_b128
    float cx = s0.y, cy = s0.z, cz = s0.w;
    if (__float_as_int(s0.x) != far) {  // rare: >1 claimer, slot0 lost
      int n = ncl[qb];
      bool found = false;
      int nn = n < 8 ? n : 8;
      for (int i2 = 1; i2 < nn; i2++) {
        float4 si = cslot[qb][i2];
        if (__float_as_int(si.x) == far) {
          cx = si.y; cy = si.z; cz = si.w; found = true;
        }
      }
      if (!found) {                  // ultra-rare (>8 claimers): exact fallback
        float x = pb[far * 3], y = pb[far * 3 + 1], z = pb[far * 3 + 2];
        cx = fmaf(m00, x, fmaf(m10, y, m20 * z));
        cy = fmaf(m11, y, m21 * z);
        cz = m22 * z;
      }
    }
    if (t == 0) {
      idx_out[b * NSAMP + k] = far;  // scan emits pre-update far
      widx[par] = 0x7fffffff;        // reset claim buffer for this step
      ncl[par] = 0;
    }

    float nc = fmaf(cx, cx, fmaf(cy, cy, cz * cz));
    float cx2 = -2.f * cx, cy2 = -2.f * cy, cz2 = -2.f * cz;
    v2f cxv = (v2f){cx2, cx2}, cyv = (v2f){cy2, cy2}, czv = (v2f){cz2, cz2};
    v2f ncv = (v2f){nc, nc};
#pragma unroll
    for (int j = 0; j < 8; j++) {    // d = n_i - 2<q,c> + n_c, packed
      v2f base = nq[j] + ncv;
      v2f d = __builtin_elementwise_fma(
          qx[j], cxv,
          __builtin_elementwise_fma(qy[j], cyv,
              __builtin_elementwise_fma(qz[j], czv, base)));
      dist[j].x = fminf(dist[j].x, d.x);
      dist[j].y = fminf(dist[j].y, d.y);
    }
    // per-thread max of 16
    float a0 = fmaxf(dist[0].x, dist[0].y);
    float a1 = fmaxf(dist[1].x, dist[1].y);
    float a2 = fmaxf(dist[2].x, dist[2].y);
    float a3 = fmaxf(dist[3].x, dist[3].y);
    float a4 = fmaxf(dist[4].x, dist[4].y);
    float a5 = fmaxf(dist[5].x, dist[5].y);
    float a6 = fmaxf(dist[6].x, dist[6].y);
    float a7 = fmaxf(dist[7].x, dist[7].y);
    float b0 = fmaxf(fmaxf(a0, a1), a2);
    float b1 = fmaxf(fmaxf(a3, a4), a5);
    float tmax = fmaxf(fmaxf(b0, b1), fmaxf(a6, a7));
    // wave butterfly (f32), then one slot per wave (R1 proven form)
    float m = tmax;
#pragma unroll
    for (int off = 32; off; off >>= 1) m = fmaxf(m, __shfl_xor(m, off, 64));
    if ((t & 63) == 0) redv[par][t >> 6] = m;
    __syncthreads();                 // barrier 1: slots visible
    float4 r0 = *(const float4*)&redv[par][0];
    float4 r1 = *(const float4*)&redv[par][4];
    float4 r2 = *(const float4*)&redv[par][8];
    float4 r3 = *(const float4*)&redv[par][12];
    float g01 = fmaxf(fmaxf(r0.x, r0.y), r0.z);
    float g02 = fmaxf(fmaxf(r0.w, r1.x), r1.y);
    float g03 = fmaxf(fmaxf(r1.z, r1.w), r2.x);
    float g04 = fmaxf(fmaxf(r2.y, r2.z), r2.w);
    float g05 = fmaxf(fmaxf(r3.x, r3.y), r3.z);
    float gmax = fmaxf(fmaxf(fmaxf(g01, g02), g03),
                       fmaxf(fmaxf(g04, g05), r3.w));
    if (tmax == gmax) {              // rare claim: carry index AND q
      // independent predicated selects, DESCENDING index order:
      // last executed write = smallest matching index (first-index tiebreak)
      int mi = 0x7fffffff; float wx = 0.f, wy = 0.f, wz = 0.f;
#pragma unroll
      for (int j = 7; j >= 0; j--) {
        int i0 = ((2 * j) << 10) + t;
        bool hy = (dist[j].y == gmax);
        mi = hy ? i0 + 1024 : mi;
        wx = hy ? qx[j].y : wx; wy = hy ? qy[j].y : wy; wz = hy ? qz[j].y : wz;
        bool hx = (dist[j].x == gmax);
        mi = hx ? i0 : mi;
        wx = hx ? qx[j].x : wx; wy = hx ? qy[j].x : wy; wz = hx ? qz[j].x : wz;
      }
      int pos = atomicAdd(&ncl[par], 1);
      if (pos < 8)
        cslot[par][pos] = make_float4(__int_as_float(mi), wx, wy, wz);
      atomicMin(&widx[par], mi);     // smallest global index wins => argmax
    }
    __syncthreads();                 // barrier 2: selection resolved
    par ^= 1;
  }
}

// ---- K2: GEMM1 over LOCAL channels only + per-batch glob base + BN1 sums --
// h1 = local_feat @ W1_loc + (gf@W1_glob + b1)   [glob part precomputed in K1]
__global__ __launch_bounds__(384) void k_gemm1(const float* p,
                                               const float* Wc,
                                               const float* bc,
                                               float* ws) {
  __shared__ __align__(16) float ct[HALF * 8];
  int t = threadIdx.x;
  int row0 = blockIdx.x * 8;
  int b = row0 >> 8;                 // 8 rows never span a batch (256 | 8)
  const int* fidx = (const int*)(ws + OFF_IDX);
  for (int sI = t; sI < 8 * HALF; sI += 384) {  // stage sampled local_feat
    int r = sI / HALF, co = sI % HALF;
    int row = row0 + r;
    int i = fidx[row];
    const float* pp = p + (b * PN + i) * 3;
    float val = bc[co];
    val = fmaf(pp[0], Wc[co], val);
    val = fmaf(pp[1], Wc[HALF + co], val);
    val = fmaf(pp[2], Wc[2 * HALF + co], val);
    ct[co * 8 + r] = val;
  }
  __syncthreads();
  const float* w1t = ws + OFF_W1T;
  float acc[8] = {0.f, 0.f, 0.f, 0.f, 0.f, 0.f, 0.f, 0.f};
  for (int c = 0; c < HALF; c++) {
    float w = w1t[c * HID + t];
    float4 a0 = *(const float4*)(ct + c * 8);
    float4 a1 = *(const float4*)(ct + c * 8 + 4);
    acc[0] = fmaf(a0.x, w, acc[0]); acc[1] = fmaf(a0.y, w, acc[1]);
    acc[2] = fmaf(a0.z, w, acc[2]); acc[3] = fmaf(a0.w, w, acc[3]);
    acc[4] = fmaf(a1.x, w, acc[4]); acc[5] = fmaf(a1.y, w, acc[5]);
    acc[6] = fmaf(a1.z, w, acc[6]); acc[7] = fmaf(a1.w, w, acc[7]);
  }
  float base = ws[OFF_GFW + b * HID + t];  // includes b1 + glob contribution
  float sv = 0.f, sq = 0.f;
#pragma unroll
  for (int r = 0; r < 8; r++) {
    float v = acc[r] + base;
    ws[OFF_H1 + (row0 + r) * HID + t] = v;
    sv += v; sq = fmaf(v, v, sq);
  }
  atomicAdd(&ws[OFF_SUM1 + t], sv);
  atomicAdd(&ws[OFF_SQ1 + t], sq);
}

// ---- K3: GEMM2 with inline BN1 finalize + ReLU on load -------------------
__global__ __launch_bounds__(384) void k_gemm2(const float* b2,
                                               const float* g1,
                                               const float* be1,
                                               float* ws) {
  __shared__ __align__(16) float ht[HID * 8];
  __shared__ float sc1s[HID], sh1s[HID];
  int t = threadIdx.x;
  int row0 = blockIdx.x * 8;
  {                                   // BN1 finalize, redundantly per block
    float m = ws[OFF_SUM1 + t] * (1.f / ROWS);
    float v = ws[OFF_SQ1 + t] * (1.f / ROWS) - m * m;
    float inv = 1.f / sqrtf(v + BN_EPS);
    float sc = inv * g1[t];
    sc1s[t] = sc;
    sh1s[t] = be1[t] - m * sc;
  }
  __syncthreads();
  for (int sI = t; sI < 8 * HID; sI += 384) {
    int r = sI / HID, c = sI % HID;
    float x = fmaf(ws[OFF_H1 + (row0 + r) * HID + c], sc1s[c], sh1s[c]);
    ht[c * 8 + r] = fmaxf(x, 0.f);
  }
  __syncthreads();
  const float* w2t = ws + OFF_W2T;
  float acc[8] = {0.f, 0.f, 0.f, 0.f, 0.f, 0.f, 0.f, 0.f};
  for (int c = 0; c < HID; c++) {
    float w = w2t[c * HID + t];
    float4 a0 = *(const float4*)(ht + c * 8);
    float4 a1 = *(const float4*)(ht + c * 8 + 4);
    acc[0] = fmaf(a0.x, w, acc[0]); acc[1] = fmaf(a0.y, w, acc[1]);
    acc[2] = fmaf(a0.z, w, acc[2]); acc[3] = fmaf(a0.w, w, acc[3]);
    acc[4] = fmaf(a1.x, w, acc[4]); acc[5] = fmaf(a1.y, w, acc[5]);
    acc[6] = fmaf(a1.z, w, acc[6]); acc[7] = fmaf(a1.w, w, acc[7]);
  }
  float bias = b2[t];
  float sv = 0.f, sq = 0.f;
#pragma unroll
  for (int r = 0; r < 8; r++) {
    float v = acc[r] + bias;
    ws[OFF_H2 + (row0 + r) * HID + t] = v;
    sv += v; sq = fmaf(v, v, sq);
  }
  atomicAdd(&ws[OFF_SUM2 + t], sv);
  atomicAdd(&ws[OFF_SQ2 + t], sq);
}

// ---- K4: inline BN2 finalize + affine + ReLU -----------------------------
__global__ __launch_bounds__(256) void k_out(const float* ws, const float* g2,
                                             const float* be2, float* out) {
  int gid = blockIdx.x * 256 + threadIdx.x;
  int i = gid * 4;
  int c = i % HID;                    // multiple of 4
  float4 h  = *(const float4*)(ws + OFF_H2 + i);
  float4 s2 = *(const float4*)(ws + OFF_SUM2 + c);
  float4 q2 = *(const float4*)(ws + OFF_SQ2 + c);
  float4 gv = *(const float4*)(g2 + c);
  float4 bv = *(const float4*)(be2 + c);
  float4 r;
#define BN2(comp) {                                                  \
    float m  = s2.comp * (1.f / ROWS);                               \
    float v  = q2.comp * (1.f / ROWS) - m * m;                       \
    float sc = (1.f / sqrtf(v + BN_EPS)) * gv.comp;                  \
    float sh = bv.comp - m * sc;                                     \
    r.comp = fmaxf(fmaf(h.comp, sc, sh), 0.f); }
  BN2(x) BN2(y) BN2(z) BN2(w)
#undef BN2
  ((float4*)out)[gid] = r;
}

extern "C" void kernel_launch(void* const* d_in, const int* in_sizes, int n_in,
                              void* d_out, int out_size, void* d_ws, size_t ws_size,
                              hipStream_t stream) {
  const float* p   = (const float*)d_in[0];
  // d_in[1] = N (int scalar, always 256)
  const float* pf  = (const float*)d_in[2];
  const float* Wf  = (const float*)d_in[3];
  const float* bfe = (const float*)d_in[4];
  const float* Wc  = (const float*)d_in[5];
  const float* bc  = (const float*)d_in[6];
  const float* W1  = (const float*)d_in[7];
  const float* b1  = (const float*)d_in[8];
  const float* g1  = (const float*)d_in[9];
  const float* be1 = (const float*)d_in[10];
  const float* W2  = (const float*)d_in[11];
  const float* b2  = (const float*)d_in[12];
  const float* g2  = (const float*)d_in[13];
  const float* be2 = (const float*)d_in[14];
  float* ws = (float*)d_ws;

  hipLaunchKernelGGL(k_main,  dim3(33),  dim3(1024), 0, stream,
                     p, Wc, pf, Wf, bfe, W1, b1, W2, ws);
  hipLaunchKernelGGL(k_gemm1, dim3(256), dim3(384), 0, stream, p, Wc, bc, ws);
  hipLaunchKernelGGL(k_gemm2, dim3(256), dim3(384), 0, stream, b2, g1, be1, ws);
  hipLaunchKernelGGL(k_out,   dim3(768), dim3(256), 0, stream,
                     ws, g2, be2, (float*)d_out);
}